// Round 17
// baseline (290.472 us; speedup 1.0000x reference)
//
#include <hip/hip_runtime.h>
#include <hip/hip_bf16.h>

#define NPTS 4096
#define KNN  32

typedef __attribute__((ext_vector_type(8))) short short8;
typedef __attribute__((ext_vector_type(4))) float floatx4;
typedef unsigned short u16x4 __attribute__((ext_vector_type(4)));

__device__ __forceinline__ unsigned short f2bf(float f) {
    unsigned u = __float_as_uint(f);
    u = (u + 0x7FFFu + ((u >> 16) & 1u)) >> 16;
    return (unsigned short)u;
}

// ---------------- Kernel 0: pack points + convert weights to bf16 ------------
__global__ __launch_bounds__(256) void prep_all(
    const float* __restrict__ x, float4* __restrict__ pts4,
    const float* __restrict__ gW0, const float* __restrict__ gW1,
    const float* __restrict__ mW0, const float* __restrict__ mW1,
    unsigned short* __restrict__ Wb0, unsigned short* __restrict__ Wb1,
    unsigned short* __restrict__ Wb2, unsigned short* __restrict__ Wb3)
{
    const int blk = blockIdx.x, t = threadIdx.x;
    if (blk < 64) {
        const int i = blk * 256 + t;                 // 0..16383 = b*4096+n
        const int b = i >> 12, n = i & (NPTS - 1);
        const float* xb = x + (size_t)b * 3 * NPTS;
        const float qx = xb[n], qy = xb[NPTS + n], qz = xb[2 * NPTS + n];
        pts4[i] = make_float4(qx, qy, qz, qx * qx + qy * qy + qz * qz);
    } else {
        const int wi = (blk - 64) * 256 + t;         // 0..655359 (exact)
        float v; unsigned short* dst;
        if (wi < 98304)       { v = gW0[wi];          dst = Wb0 + wi; }
        else if (wi < 360448) { v = gW1[wi - 98304];  dst = Wb1 + (wi - 98304); }
        else if (wi < 622592) { v = mW0[wi - 360448]; dst = Wb2 + (wi - 360448); }
        else                  { v = mW1[wi - 622592]; dst = Wb3 + (wi - 622592); }
        *dst = f2bf(v);
    }
}

// ---------------- Kernel 1: exact KNN, block per query -----------------------
// 8 fixed prefix iterations (9-bit sign+exponent) with cntHi TRACKING (count
// at current hi's octave top; init 4096 = all finite keys <= 0xFF7FFFFF, so
// the never-updated hi=0x1FE case is exact) -> the refinement's initial count
// pass is free. Rare dynamic mantissa refinement while count > 256. Exit
// invariant: 33 <= count(thrF) <= 256 -> collect never overflows -> exact
// deterministic top-33 by (key, idx); ranks 1..32 emitted (rank 0 = self).
__global__ __launch_bounds__(256) void knn_kernel13(const float4* __restrict__ pts4,
                                                    int* __restrict__ knn_out)
{
    __shared__ unsigned sred[2][4];
    __shared__ unsigned long long C[256];
    __shared__ unsigned ccnt;

    const int t = threadIdx.x, wid = t >> 6, lane = t & 63;
    const int q = blockIdx.x, b = q >> 12, n = q & (NPTS - 1);
    const float4* P = pts4 + ((size_t)b << 12);
    const float4 s = P[n];
    const float px = s.x, py = s.y, pz = s.z, sqn = s.w;

    if (t == 0) ccnt = 0u;

    unsigned key[16];
    #pragma unroll
    for (int g = 0; g < 4; ++g) {
        float4 c0 = P[((g * 4 + 0) << 8) + t];
        float4 c1 = P[((g * 4 + 1) << 8) + t];
        float4 c2 = P[((g * 4 + 2) << 8) + t];
        float4 c3 = P[((g * 4 + 3) << 8) + t];
        float d0 = (sqn + c0.w) - 2.0f * (px * c0.x + py * c0.y + pz * c0.z);
        float d1 = (sqn + c1.w) - 2.0f * (px * c1.x + py * c1.y + pz * c1.z);
        float d2 = (sqn + c2.w) - 2.0f * (px * c2.x + py * c2.y + pz * c2.z);
        float d3 = (sqn + c3.w) - 2.0f * (px * c3.x + py * c3.y + pz * c3.z);
        unsigned u0 = __float_as_uint(d0), u1 = __float_as_uint(d1);
        unsigned u2 = __float_as_uint(d2), u3 = __float_as_uint(d3);
        key[g * 4 + 0] = (u0 & 0x80000000u) ? ~u0 : (u0 | 0x80000000u);
        key[g * 4 + 1] = (u1 & 0x80000000u) ? ~u1 : (u1 | 0x80000000u);
        key[g * 4 + 2] = (u2 & 0x80000000u) ? ~u2 : (u2 | 0x80000000u);
        key[g * 4 + 3] = (u3 & 0x80000000u) ? ~u3 : (u3 | 0x80000000u);
    }

    int pp = 0;   // count-pass parity (2-slot sred scheme, 1 barrier/pass)
    auto countLE = [&](unsigned thr) -> unsigned {
        unsigned c = 0;
        #pragma unroll
        for (int r = 0; r < 16; ++r)
            c += (unsigned)__popcll(__ballot(key[r] <= thr));
        if (lane == 0) sred[pp & 1][wid] = c;
        __syncthreads();
        const unsigned g = sred[pp & 1][0] + sred[pp & 1][1] +
                           sred[pp & 1][2] + sred[pp & 1][3];
        ++pp;
        return g;
    };

    // fixed 8-iteration search on 9-bit prefix, tracking count at hi's top
    unsigned lo = 0x100u, hi = 0x1FEu, cntHi = 4096u;
    for (int it = 0; it < 8; ++it) {
        const unsigned mid = (lo + hi) >> 1;
        const unsigned g = countLE((mid << 23) | 0x7FFFFFu);
        if (g >= 33u) { hi = mid; cntHi = g; } else lo = mid + 1u;
    }
    // refinement: shrink threshold until candidate count <= 256 (rare)
    unsigned loK = lo << 23;
    unsigned hiK = (lo << 23) | 0x7FFFFFu;
    unsigned cntF = cntHi;                    // == count(hiK), >= 33
    while (cntF > 256u && loK < hiK) {
        const unsigned midK = loK + ((hiK - loK) >> 1);
        const unsigned c = countLE(midK);
        if (c >= 33u) { hiK = midK; cntF = c; } else loK = midK + 1u;
    }
    const unsigned thrF = hiK;

    #pragma unroll
    for (int r = 0; r < 16; ++r) {
        if (key[r] <= thrF) {
            unsigned p = atomicAdd(&ccnt, 1u);
            if (p < 256u)
                C[p] = ((unsigned long long)key[r] << 32) |
                       (unsigned)((r << 8) + t);
        }
    }
    __syncthreads();

    int nc = (int)ccnt; if (nc > 256) nc = 256;   // cntF <= 256 guaranteed
    if (t < nc) {
        const unsigned long long me = C[t];
        int rank = 0;
        for (int j = 0; j < nc; ++j) rank += (C[j] < me) ? 1 : 0;
        if (rank >= 1 && rank <= KNN)
            knn_out[(size_t)q * KNN + (rank - 1)] = (int)(me & 0xFFFFFFFFu);
    }
}

// ---------------- Kernel 2: per-point 3-layer MLP -> F bf16 [b][n][384] ------
__global__ __launch_bounds__(256) void pointmlp_kernel(
    const float* __restrict__ x,
    const float* __restrict__ sW0, const float* __restrict__ sb0,
    const float* __restrict__ sW1, const float* __restrict__ sb1,
    const float* __restrict__ sW2, const float* __restrict__ sb2,
    unsigned short* __restrict__ F)
{
    __shared__ __align__(16) float BUF[8192];
    __shared__ __align__(16) float h1s[64 * 36];
    __shared__ float b1s[64];
    __shared__ float b2s[128];
    __shared__ float pts[3 * 33];

    const int t = threadIdx.x;
    const int s = blockIdx.y;
    const int tile = blockIdx.x;
    const int b = tile >> 7;
    const int j0 = (tile & 127) << 5;
    const float* xb = x + (size_t)b * 3 * NPTS;

    if (t < 192) BUF[t] = sW0[s * 192 + t];
    else if (t < 256) BUF[t] = sb0[s * 64 + (t - 192)];
    if (t < 64) b1s[t] = sb1[s * 64 + t];
    if (t < 128) b2s[t] = sb2[s * 128 + t];
    if (t < 96) { int c = t >> 5, p = t & 31; pts[c * 33 + p] = xb[c * NPTS + j0 + p]; }
    {
        const float* W1 = sW1 + (size_t)s * 4096;
        int o = t & 63, q = t >> 6;
        #pragma unroll
        for (int r = 0; r < 4; ++r) {
            float4 w = *(const float4*)(W1 + o * 64 + q * 16 + r * 4);
            int i = q * 16 + r * 4;
            BUF[256 + (i + 0) * 64 + o] = w.x;
            BUF[256 + (i + 1) * 64 + o] = w.y;
            BUF[256 + (i + 2) * 64 + o] = w.z;
            BUF[256 + (i + 3) * 64 + o] = w.w;
        }
    }
    __syncthreads();
    const int o = t & 63, pg = t >> 6;
    float* h0 = BUF + 4352;
    {
        float w0 = BUF[o * 3], w1 = BUF[o * 3 + 1], w2 = BUF[o * 3 + 2], bb = BUF[192 + o];
        #pragma unroll
        for (int p = 0; p < 8; ++p) {
            int pp = pg * 8 + p;
            float a = bb + w0 * pts[pp] + w1 * pts[33 + pp] + w2 * pts[66 + pp];
            h0[o * 36 + pp] = fmaxf(a, 0.0f);
        }
    }
    __syncthreads();
    {
        float acc[8];
        #pragma unroll
        for (int p = 0; p < 8; ++p) acc[p] = b1s[o];
        for (int i = 0; i < 64; ++i) {
            float w = BUF[256 + i * 64 + o];
            float4 ha = *(const float4*)&h0[i * 36 + pg * 8];
            float4 hb = *(const float4*)&h0[i * 36 + pg * 8 + 4];
            acc[0] += w * ha.x; acc[1] += w * ha.y; acc[2] += w * ha.z; acc[3] += w * ha.w;
            acc[4] += w * hb.x; acc[5] += w * hb.y; acc[6] += w * hb.z; acc[7] += w * hb.w;
        }
        #pragma unroll
        for (int p = 0; p < 8; ++p) h1s[o * 36 + pg * 8 + p] = fmaxf(acc[p], 0.0f);
    }
    __syncthreads();
    {
        const float* W2 = sW2 + (size_t)s * 8192;
        int o2 = t & 127, q = t >> 7;
        #pragma unroll
        for (int r = 0; r < 8; ++r) {
            float4 w = *(const float4*)(W2 + o2 * 64 + q * 32 + r * 4);
            int i = q * 32 + r * 4;
            BUF[(i + 0) * 128 + o2] = w.x;
            BUF[(i + 1) * 128 + o2] = w.y;
            BUF[(i + 2) * 128 + o2] = w.z;
            BUF[(i + 3) * 128 + o2] = w.w;
        }
    }
    __syncthreads();
    {
        int o2 = t & 127, ph = t >> 7;
        float acc[16];
        #pragma unroll
        for (int p = 0; p < 16; ++p) acc[p] = b2s[o2];
        for (int i = 0; i < 64; ++i) {
            float w = BUF[i * 128 + o2];
            float4 ha = *(const float4*)&h1s[i * 36 + ph * 16];
            float4 hb = *(const float4*)&h1s[i * 36 + ph * 16 + 4];
            float4 hc = *(const float4*)&h1s[i * 36 + ph * 16 + 8];
            float4 hd = *(const float4*)&h1s[i * 36 + ph * 16 + 12];
            acc[0]  += w * ha.x; acc[1]  += w * ha.y; acc[2]  += w * ha.z; acc[3]  += w * ha.w;
            acc[4]  += w * hb.x; acc[5]  += w * hb.y; acc[6]  += w * hb.z; acc[7]  += w * hb.w;
            acc[8]  += w * hc.x; acc[9]  += w * hc.y; acc[10] += w * hc.z; acc[11] += w * hc.w;
            acc[12] += w * hd.x; acc[13] += w * hd.y; acc[14] += w * hd.z; acc[15] += w * hd.w;
        }
        #pragma unroll
        for (int p = 0; p < 16; ++p) {
            int j = j0 + ph * 16 + p;
            F[((size_t)b * NPTS + j) * 384 + s * 128 + o2] = f2bf(fmaxf(acc[p], 0.0f));
        }
    }
}

// ---------------- Kernel 3: gather-max, 4 channels/lane, 2 queries/block -----
// uint16 compare valid: post-relu bf16 (>=0) bit patterns are value-monotone.
// q0=2*blk, q1=2*blk+1 share a batch (odd q1 can't cross a 4096 boundary).
__global__ __launch_bounds__(192) void maxgather_bf16(
    const unsigned short* __restrict__ F, const int* __restrict__ knn,
    unsigned short* __restrict__ pt)
{
    __shared__ int idxS[64];
    const int blk = blockIdx.x;
    const int t = threadIdx.x;
    if (t < 64) idxS[t] = knn[(size_t)(blk * 2) * KNN + t];
    __syncthreads();
    const int qsel = (t >= 96) ? 1 : 0;
    const int q = blk * 2 + qsel;
    const int b = q >> 12;
    const int lq = t - qsel * 96;        // channel-quad 0..95
    const unsigned short* Fb = F + (size_t)b * NPTS * 384 + lq * 4;
    const int* myIdx = idxS + qsel * KNN;
    u16x4 m = (u16x4)0;
    #pragma unroll 8
    for (int k = 0; k < KNN; ++k) {
        u16x4 v = *(const u16x4*)(Fb + (size_t)myIdx[k] * 384);
        m = __builtin_elementwise_max(m, v);
    }
    *(u16x4*)(pt + (size_t)q * 384 + lq * 4) = m;
}

// ---------------- Kernel 4: bf16 MFMA GEMM + bias + relu (R10-passing) -------
template<int DO_ROWMAX>
__global__ __launch_bounds__(256) void gemm_bf16(
    const unsigned short* __restrict__ Wb, const unsigned short* __restrict__ Bt,
    const float* __restrict__ bias, void* __restrict__ outp,
    float* __restrict__ gfeat, int M, int K)
{
    __shared__ __align__(16) unsigned short As[128 * 40]; // [m][k] pad 40
    __shared__ __align__(16) unsigned short Bs[128 * 40]; // [n][k] pad 40
    __shared__ float biasS[128];
    __shared__ int redI[128];

    const int t = threadIdx.x;
    const int b = blockIdx.z;
    const int m0 = blockIdx.x * 128;
    const int n0 = blockIdx.y * 128;
    if (t < 128) biasS[t] = bias[m0 + t];
    if (DO_ROWMAX && t < 128) redI[t] = 0;

    const int wave = t >> 6, lane = t & 63, quad = lane >> 4, l15 = lane & 15;
    const int wr = wave >> 1, wc = wave & 1;

    const int am = t & 127, akh = t >> 7;
    const unsigned short* Wp = Wb + (size_t)(m0 + am) * K + akh * 16;
    const int bn = t >> 2, bq = t & 3;
    const unsigned short* Bp = Bt + ((size_t)b * NPTS + n0) * K;

    floatx4 acc[16];
    #pragma unroll
    for (int i = 0; i < 16; ++i) acc[i] = (floatx4){0.f, 0.f, 0.f, 0.f};

    const int nk = K >> 5;
    for (int kt = 0; kt < nk; ++kt) {
        const int k0 = kt << 5;
        uint4 av0 = *(const uint4*)(Wp + k0);
        uint4 av1 = *(const uint4*)(Wp + k0 + 8);
        uint4 bv0 = *(const uint4*)(Bp + (size_t)bn * K + k0 + bq * 8);
        uint4 bv1 = *(const uint4*)(Bp + (size_t)(bn + 64) * K + k0 + bq * 8);
        __syncthreads();
        {
            uint4* dst = (uint4*)&As[am * 40 + akh * 16];
            dst[0] = av0;
            dst[1] = av1;
            *(uint4*)&Bs[bn * 40 + bq * 8] = bv0;
            *(uint4*)&Bs[(bn + 64) * 40 + bq * 8] = bv1;
        }
        __syncthreads();
        short8 af[4], bfv[4];
        #pragma unroll
        for (int i = 0; i < 4; ++i)
            af[i] = *(const short8*)&As[(wr * 64 + i * 16 + l15) * 40 + quad * 8];
        #pragma unroll
        for (int j = 0; j < 4; ++j)
            bfv[j] = *(const short8*)&Bs[(wc * 64 + j * 16 + l15) * 40 + quad * 8];
        #pragma unroll
        for (int i = 0; i < 4; ++i)
            #pragma unroll
            for (int j = 0; j < 4; ++j)
                acc[i * 4 + j] = __builtin_amdgcn_mfma_f32_16x16x32_bf16(
                    af[i], bfv[j], acc[i * 4 + j], 0, 0, 0);
    }

    #pragma unroll
    for (int i = 0; i < 4; ++i) {
        const int mbase = wr * 64 + i * 16 + quad * 4;
        float rm0 = 0.f, rm1 = 0.f, rm2 = 0.f, rm3 = 0.f;
        #pragma unroll
        for (int j = 0; j < 4; ++j) {
            const int n = n0 + wc * 64 + j * 16 + l15;
            float v0 = fmaxf(acc[i * 4 + j][0] + biasS[mbase + 0], 0.f);
            float v1 = fmaxf(acc[i * 4 + j][1] + biasS[mbase + 1], 0.f);
            float v2 = fmaxf(acc[i * 4 + j][2] + biasS[mbase + 2], 0.f);
            float v3 = fmaxf(acc[i * 4 + j][3] + biasS[mbase + 3], 0.f);
            if (DO_ROWMAX) {
                rm0 = fmaxf(rm0, v0); rm1 = fmaxf(rm1, v1);
                rm2 = fmaxf(rm2, v2); rm3 = fmaxf(rm3, v3);
            }
            ushort4 pk;
            pk.x = f2bf(v0); pk.y = f2bf(v1); pk.z = f2bf(v2); pk.w = f2bf(v3);
            *(ushort4*)((unsigned short*)outp +
                        ((size_t)b * NPTS + n) * M + m0 + mbase) = pk;
        }
        if (DO_ROWMAX) {
            atomicMax(&redI[mbase + 0], __float_as_int(rm0));
            atomicMax(&redI[mbase + 1], __float_as_int(rm1));
            atomicMax(&redI[mbase + 2], __float_as_int(rm2));
            atomicMax(&redI[mbase + 3], __float_as_int(rm3));
        }
    }
    if (DO_ROWMAX) {
        __syncthreads();
        if (t < 128)       // d_out zeroed before launch; values >= 0 -> safe
            atomicMax((int*)&gfeat[(size_t)b * 1024 + m0 + t], redI[t]);
    }
}

// ---------------- Kernel 5: fused head = gemm3 + gemm4 -----------------------
__global__ __launch_bounds__(256) void fused_head(
    const unsigned short* __restrict__ Wb2, const unsigned short* __restrict__ Wb3,
    const float* __restrict__ mb0, const float* __restrict__ mb1,
    const unsigned short* __restrict__ gft, float* __restrict__ outp)
{
    __shared__ __align__(16) unsigned short As[256 * 40];
    __shared__ __align__(16) unsigned short Bs[64 * 40];
    __shared__ __align__(16) unsigned short H[64 * 264];
    __shared__ float b0s[256];
    __shared__ float b1s[128];

    const int t = threadIdx.x;
    const int n0 = blockIdx.x * 64;
    const int b = blockIdx.y;
    b0s[t] = mb0[t];
    if (t < 128) b1s[t] = mb1[t];

    const int wave = t >> 6, lane = t & 63, quad = lane >> 4, l15 = lane & 15;

    // ---- phase 1: C1[256m x 64n], K = 1024 ----
    const unsigned short* Ap = Wb2 + (size_t)t * 1024;
    const int bn = t >> 2, bq = t & 3;
    const unsigned short* Bp = gft + ((size_t)b * NPTS + n0) * 1024;

    floatx4 acc[16];
    #pragma unroll
    for (int i = 0; i < 16; ++i) acc[i] = (floatx4){0.f, 0.f, 0.f, 0.f};

    for (int kt = 0; kt < 32; ++kt) {
        const int k0 = kt << 5;
        uint4 a0 = *(const uint4*)(Ap + k0);
        uint4 a1 = *(const uint4*)(Ap + k0 + 8);
        uint4 a2 = *(const uint4*)(Ap + k0 + 16);
        uint4 a3 = *(const uint4*)(Ap + k0 + 24);
        uint4 bv = *(const uint4*)(Bp + (size_t)bn * 1024 + k0 + bq * 8);
        __syncthreads();
        *(uint4*)&As[t * 40 + 0]  = a0;
        *(uint4*)&As[t * 40 + 8]  = a1;
        *(uint4*)&As[t * 40 + 16] = a2;
        *(uint4*)&As[t * 40 + 24] = a3;
        *(uint4*)&Bs[bn * 40 + bq * 8] = bv;
        __syncthreads();
        short8 af[4], bfv[4];
        #pragma unroll
        for (int i = 0; i < 4; ++i)
            af[i] = *(const short8*)&As[(wave * 64 + i * 16 + l15) * 40 + quad * 8];
        #pragma unroll
        for (int j = 0; j < 4; ++j)
            bfv[j] = *(const short8*)&Bs[(j * 16 + l15) * 40 + quad * 8];
        #pragma unroll
        for (int i = 0; i < 4; ++i)
            #pragma unroll
            for (int j = 0; j < 4; ++j)
                acc[i * 4 + j] = __builtin_amdgcn_mfma_f32_16x16x32_bf16(
                    af[i], bfv[j], acc[i * 4 + j], 0, 0, 0);
    }
    #pragma unroll
    for (int i = 0; i < 4; ++i) {
        const int mbase = wave * 64 + i * 16 + quad * 4;
        #pragma unroll
        for (int j = 0; j < 4; ++j) {
            const int nl = j * 16 + l15;
            ushort4 pk;
            pk.x = f2bf(fmaxf(acc[i * 4 + j][0] + b0s[mbase + 0], 0.f));
            pk.y = f2bf(fmaxf(acc[i * 4 + j][1] + b0s[mbase + 1], 0.f));
            pk.z = f2bf(fmaxf(acc[i * 4 + j][2] + b0s[mbase + 2], 0.f));
            pk.w = f2bf(fmaxf(acc[i * 4 + j][3] + b0s[mbase + 3], 0.f));
            *(ushort4*)&H[nl * 264 + mbase] = pk;
        }
    }

    // ---- phase 2: C2[128m x 64n], K = 256 (B = H in LDS) ----
    floatx4 acc2[8];
    #pragma unroll
    for (int i = 0; i < 8; ++i) acc2[i] = (floatx4){0.f, 0.f, 0.f, 0.f};
    const int am2 = t & 127, ah = t >> 7;

    for (int kt = 0; kt < 8; ++kt) {
        const int k0 = kt << 5;
        uint4 a0 = *(const uint4*)(Wb3 + (size_t)am2 * 256 + k0 + ah * 16);
        uint4 a1 = *(const uint4*)(Wb3 + (size_t)am2 * 256 + k0 + ah * 16 + 8);
        __syncthreads();
        *(uint4*)&As[am2 * 40 + ah * 16]     = a0;
        *(uint4*)&As[am2 * 40 + ah * 16 + 8] = a1;
        __syncthreads();
        short8 af2[2], bf2[4];
        #pragma unroll
        for (int i = 0; i < 2; ++i)
            af2[i] = *(const short8*)&As[(wave * 32 + i * 16 + l15) * 40 + quad * 8];
        #pragma unroll
        for (int j = 0; j < 4; ++j)
            bf2[j] = *(const short8*)&H[(j * 16 + l15) * 264 + k0 + quad * 8];
        #pragma unroll
        for (int i = 0; i < 2; ++i)
            #pragma unroll
            for (int j = 0; j < 4; ++j)
                acc2[i * 4 + j] = __builtin_amdgcn_mfma_f32_16x16x32_bf16(
                    af2[i], bf2[j], acc2[i * 4 + j], 0, 0, 0);
    }
    #pragma unroll
    for (int i = 0; i < 2; ++i) {
        const int m2 = wave * 32 + i * 16 + quad * 4;
        #pragma unroll
        for (int j = 0; j < 4; ++j) {
            const int n = n0 + j * 16 + l15;
            float* o = outp + ((size_t)b * 128 + m2) * NPTS + n;
            o[0 * NPTS] = fmaxf(acc2[i * 4 + j][0] + b1s[m2 + 0], 0.f);
            o[1 * NPTS] = fmaxf(acc2[i * 4 + j][1] + b1s[m2 + 1], 0.f);
            o[2 * NPTS] = fmaxf(acc2[i * 4 + j][2] + b1s[m2 + 2], 0.f);
            o[3 * NPTS] = fmaxf(acc2[i * 4 + j][3] + b1s[m2 + 3], 0.f);
        }
    }
}

extern "C" void kernel_launch(void* const* d_in, const int* in_sizes, int n_in,
                              void* d_out, int out_size, void* d_ws, size_t ws_size,
                              hipStream_t stream)
{
    const float* x   = (const float*)d_in[0];
    const float* sW0 = (const float*)d_in[1];
    const float* sb0 = (const float*)d_in[2];
    const float* sW1 = (const float*)d_in[3];
    const float* sb1 = (const float*)d_in[4];
    const float* sW2 = (const float*)d_in[5];
    const float* sb2 = (const float*)d_in[6];
    const float* gW0 = (const float*)d_in[7];
    const float* gb0 = (const float*)d_in[8];
    const float* gW1 = (const float*)d_in[9];
    const float* gb1 = (const float*)d_in[10];
    const float* mW0 = (const float*)d_in[11];
    const float* mb0 = (const float*)d_in[12];
    const float* mW1 = (const float*)d_in[13];
    const float* mb1 = (const float*)d_in[14];
    float* outp = (float*)d_out;

    char* ws = (char*)d_ws;
    int*            idx     = (int*)(ws);                        // 2 MB
    float4*         pts4    = (float4*)(ws + 2097152u);          // 256 KB
    unsigned short* Wb0     = (unsigned short*)(ws + 2359296u);  // 192 KB  gW0 bf16
    unsigned short* Wb1     = (unsigned short*)(ws + 2555904u);  // 512 KB  gW1 bf16
    unsigned short* Wb2     = (unsigned short*)(ws + 3080192u);  // 512 KB  mW0 bf16
    unsigned short* Wb3     = (unsigned short*)(ws + 3604480u);  // 64 KB   mW1 bf16
    unsigned short* F       = (unsigned short*)(ws + 4194304u);  // 12.6 MB [b][n][384] bf16
    unsigned short* point_t = (unsigned short*)(ws + 18874368u); // 12.6 MB [b][n][384] bf16
    unsigned short* gf0t    = (unsigned short*)(ws + 33554432u); // 8.4 MB  [b][n][256] bf16
    unsigned short* gft     = (unsigned short*)(ws + 50331648u); // 33.6 MB [b][n][1024] bf16

    prep_all<<<dim3(2624), dim3(256), 0, stream>>>(
        x, pts4, gW0, gW1, mW0, mW1, Wb0, Wb1, Wb2, Wb3);
    knn_kernel13<<<dim3(16384), dim3(256), 0, stream>>>(pts4, idx);
    pointmlp_kernel<<<dim3(512, 3), dim3(256), 0, stream>>>(
        x, sW0, sb0, sW1, sb1, sW2, sb2, F);
    maxgather_bf16<<<dim3(8192), dim3(192), 0, stream>>>(F, idx, point_t);
    gemm_bf16<0><<<dim3(2, 32, 4), dim3(256), 0, stream>>>(
        Wb0, point_t, gb0, gf0t, nullptr, 256, 384);
    gemm_bf16<1><<<dim3(8, 32, 4), dim3(256), 0, stream>>>(
        Wb1, gf0t, gb1, gft, outp, 1024, 256);
    fused_head<<<dim3(64, 4), dim3(256), 0, stream>>>(
        Wb2, Wb3, mb0, mb1, gft, outp + 4096);
}

// Round 18
// 269.799 us; speedup vs baseline: 1.0766x; 1.0766x over previous
//
#include <hip/hip_runtime.h>
#include <hip/hip_bf16.h>

#define NPTS 4096
#define KNN  32

typedef __attribute__((ext_vector_type(8))) short short8;
typedef __attribute__((ext_vector_type(4))) float floatx4;
typedef unsigned short u16x2 __attribute__((ext_vector_type(2)));

__device__ __forceinline__ unsigned short f2bf(float f) {
    unsigned u = __float_as_uint(f);
    u = (u + 0x7FFFu + ((u >> 16) & 1u)) >> 16;
    return (unsigned short)u;
}

// ---------------- Kernel 0: pack points + convert weights to bf16 ------------
// blocks [0,64): pts4. blocks [64,2768): fp32->bf16 weights
// gW0 98304 | gW1 262144 | mW0 262144 | mW1 32768 | sW1 12288 | sW2 24576
__global__ __launch_bounds__(256) void prep_all(
    const float* __restrict__ x, float4* __restrict__ pts4,
    const float* __restrict__ gW0, const float* __restrict__ gW1,
    const float* __restrict__ mW0, const float* __restrict__ mW1,
    const float* __restrict__ sW1, const float* __restrict__ sW2,
    unsigned short* __restrict__ Wb0, unsigned short* __restrict__ Wb1,
    unsigned short* __restrict__ Wb2, unsigned short* __restrict__ Wb3,
    unsigned short* __restrict__ Wb4, unsigned short* __restrict__ Wb5)
{
    const int blk = blockIdx.x, t = threadIdx.x;
    if (blk < 64) {
        const int i = blk * 256 + t;                 // 0..16383 = b*4096+n
        const int b = i >> 12, n = i & (NPTS - 1);
        const float* xb = x + (size_t)b * 3 * NPTS;
        const float qx = xb[n], qy = xb[NPTS + n], qz = xb[2 * NPTS + n];
        pts4[i] = make_float4(qx, qy, qz, qx * qx + qy * qy + qz * qz);
    } else {
        const int wi = (blk - 64) * 256 + t;         // 0..692223 (exact)
        float v; unsigned short* dst;
        if (wi < 98304)       { v = gW0[wi];          dst = Wb0 + wi; }
        else if (wi < 360448) { v = gW1[wi - 98304];  dst = Wb1 + (wi - 98304); }
        else if (wi < 622592) { v = mW0[wi - 360448]; dst = Wb2 + (wi - 360448); }
        else if (wi < 655360) { v = mW1[wi - 622592]; dst = Wb3 + (wi - 622592); }
        else if (wi < 667648) { v = sW1[wi - 655360]; dst = Wb4 + (wi - 655360); }
        else                  { v = sW2[wi - 667648]; dst = Wb5 + (wi - 667648); }
        *dst = f2bf(v);
    }
}

// ---------------- Kernel 1: exact KNN, block per query (R17-passing) ---------
__global__ __launch_bounds__(256) void knn_kernel13(const float4* __restrict__ pts4,
                                                    int* __restrict__ knn_out)
{
    __shared__ unsigned sred[2][4];
    __shared__ unsigned long long C[256];
    __shared__ unsigned ccnt;

    const int t = threadIdx.x, wid = t >> 6, lane = t & 63;
    const int q = blockIdx.x, b = q >> 12, n = q & (NPTS - 1);
    const float4* P = pts4 + ((size_t)b << 12);
    const float4 s = P[n];
    const float px = s.x, py = s.y, pz = s.z, sqn = s.w;

    if (t == 0) ccnt = 0u;

    unsigned key[16];
    #pragma unroll
    for (int g = 0; g < 4; ++g) {
        float4 c0 = P[((g * 4 + 0) << 8) + t];
        float4 c1 = P[((g * 4 + 1) << 8) + t];
        float4 c2 = P[((g * 4 + 2) << 8) + t];
        float4 c3 = P[((g * 4 + 3) << 8) + t];
        float d0 = (sqn + c0.w) - 2.0f * (px * c0.x + py * c0.y + pz * c0.z);
        float d1 = (sqn + c1.w) - 2.0f * (px * c1.x + py * c1.y + pz * c1.z);
        float d2 = (sqn + c2.w) - 2.0f * (px * c2.x + py * c2.y + pz * c2.z);
        float d3 = (sqn + c3.w) - 2.0f * (px * c3.x + py * c3.y + pz * c3.z);
        unsigned u0 = __float_as_uint(d0), u1 = __float_as_uint(d1);
        unsigned u2 = __float_as_uint(d2), u3 = __float_as_uint(d3);
        key[g * 4 + 0] = (u0 & 0x80000000u) ? ~u0 : (u0 | 0x80000000u);
        key[g * 4 + 1] = (u1 & 0x80000000u) ? ~u1 : (u1 | 0x80000000u);
        key[g * 4 + 2] = (u2 & 0x80000000u) ? ~u2 : (u2 | 0x80000000u);
        key[g * 4 + 3] = (u3 & 0x80000000u) ? ~u3 : (u3 | 0x80000000u);
    }

    int pp = 0;
    auto countLE = [&](unsigned thr) -> unsigned {
        unsigned c = 0;
        #pragma unroll
        for (int r = 0; r < 16; ++r)
            c += (unsigned)__popcll(__ballot(key[r] <= thr));
        if (lane == 0) sred[pp & 1][wid] = c;
        __syncthreads();
        const unsigned g = sred[pp & 1][0] + sred[pp & 1][1] +
                           sred[pp & 1][2] + sred[pp & 1][3];
        ++pp;
        return g;
    };

    unsigned lo = 0x100u, hi = 0x1FEu, cntHi = 4096u;
    for (int it = 0; it < 8; ++it) {
        const unsigned mid = (lo + hi) >> 1;
        const unsigned g = countLE((mid << 23) | 0x7FFFFFu);
        if (g >= 33u) { hi = mid; cntHi = g; } else lo = mid + 1u;
    }
    unsigned loK = lo << 23;
    unsigned hiK = (lo << 23) | 0x7FFFFFu;
    unsigned cntF = cntHi;
    while (cntF > 256u && loK < hiK) {
        const unsigned midK = loK + ((hiK - loK) >> 1);
        const unsigned c = countLE(midK);
        if (c >= 33u) { hiK = midK; cntF = c; } else loK = midK + 1u;
    }
    const unsigned thrF = hiK;

    #pragma unroll
    for (int r = 0; r < 16; ++r) {
        if (key[r] <= thrF) {
            unsigned p = atomicAdd(&ccnt, 1u);
            if (p < 256u)
                C[p] = ((unsigned long long)key[r] << 32) |
                       (unsigned)((r << 8) + t);
        }
    }
    __syncthreads();

    int nc = (int)ccnt; if (nc > 256) nc = 256;
    if (t < nc) {
        const unsigned long long me = C[t];
        int rank = 0;
        for (int j = 0; j < nc; ++j) rank += (C[j] < me) ? 1 : 0;
        if (rank >= 1 && rank <= KNN)
            knn_out[(size_t)q * KNN + (rank - 1)] = (int)(me & 0xFFFFFFFFu);
    }
}

// ---------------- Kernel 2: per-point MLP, layers 2-3 on MFMA ----------------
// Block = 32 points x 1 scale. L1 (3->64) fp32 -> h0T[p][i] bf16 (B-frag
// layout). L2: h1[64][32] = relu(W1.h0+b1) via 8 16x16x32 tiles -> h1T[p][o].
// L3: F = relu(W2.h1+b2) via 16 tiles. Rows padded to 72 shorts (144 B = 9x16,
// 2-way bank aliasing = free). Weights pre-converted bf16 (Wb4/Wb5).
__global__ __launch_bounds__(256) void pointmlp_mfma(
    const float* __restrict__ x,
    const float* __restrict__ sW0, const float* __restrict__ sb0,
    const unsigned short* __restrict__ W1b, const float* __restrict__ sb1,
    const unsigned short* __restrict__ W2b, const float* __restrict__ sb2,
    unsigned short* __restrict__ F)
{
    __shared__ __align__(16) unsigned short W1s[64 * 72];
    __shared__ __align__(16) unsigned short W2s[128 * 72];
    __shared__ __align__(16) unsigned short h0T[32 * 72];
    __shared__ __align__(16) unsigned short h1T[32 * 72];
    __shared__ float W0s[192];
    __shared__ float b0s[64], b1s[64], b2s[128];
    __shared__ float pts[3 * 33];

    const int t = threadIdx.x;
    const int s = blockIdx.y;
    const int tile = blockIdx.x;
    const int b = tile >> 7;
    const int j0 = (tile & 127) << 5;
    const float* xb = x + (size_t)b * 3 * NPTS;

    if (t < 192) W0s[t] = sW0[s * 192 + t];
    if (t < 64) b0s[t] = sb0[s * 64 + t];
    if (t >= 64 && t < 128) b1s[t - 64] = sb1[s * 64 + (t - 64)];
    if (t < 128) b2s[t] = sb2[s * 128 + t];
    if (t < 96) { int c = t >> 5, p = t & 31; pts[c * 33 + p] = xb[c * NPTS + j0 + p]; }
    {   // W1 64x64 bf16 -> LDS [o][i] pad 72
        const int o = t & 63, qq = t >> 6;
        const unsigned short* src = W1b + (size_t)s * 4096 + o * 64 + qq * 16;
        *(uint4*)&W1s[o * 72 + qq * 16]     = *(const uint4*)src;
        *(uint4*)&W1s[o * 72 + qq * 16 + 8] = *(const uint4*)(src + 8);
    }
    {   // W2 128x64 bf16 -> LDS [o2][i] pad 72
        const int o2 = t & 127, hh = t >> 7;
        const unsigned short* src = W2b + (size_t)s * 8192 + o2 * 64 + hh * 32;
        *(uint4*)&W2s[o2 * 72 + hh * 32]      = *(const uint4*)src;
        *(uint4*)&W2s[o2 * 72 + hh * 32 + 8]  = *(const uint4*)(src + 8);
        *(uint4*)&W2s[o2 * 72 + hh * 32 + 16] = *(const uint4*)(src + 16);
        *(uint4*)&W2s[o2 * 72 + hh * 32 + 24] = *(const uint4*)(src + 24);
    }
    __syncthreads();

    {   // layer 1 (fp32): h0T[p][og*8..+7]
        const int p = t & 31, og = t >> 5;
        const float xx = pts[p], yy = pts[33 + p], zz = pts[66 + p];
        unsigned short hv[8];
        #pragma unroll
        for (int r = 0; r < 8; ++r) {
            const int o = og * 8 + r;
            float a = b0s[o] + W0s[o * 3] * xx + W0s[o * 3 + 1] * yy
                    + W0s[o * 3 + 2] * zz;
            hv[r] = f2bf(fmaxf(a, 0.0f));
        }
        *(uint4*)&h0T[p * 72 + og * 8] = *(const uint4*)hv;
    }
    __syncthreads();

    const int w = t >> 6, lane = t & 63, quad = lane >> 4, l15 = lane & 15;

    {   // layer 2: wave w owns m-tile w*16; ni over 2 n-tiles
        #pragma unroll
        for (int ni = 0; ni < 2; ++ni) {
            floatx4 acc = (floatx4){0.f, 0.f, 0.f, 0.f};
            #pragma unroll
            for (int k0 = 0; k0 < 2; ++k0) {
                short8 aF = *(const short8*)&W1s[(w * 16 + l15) * 72 + k0 * 32 + quad * 8];
                short8 bF = *(const short8*)&h0T[(ni * 16 + l15) * 72 + k0 * 32 + quad * 8];
                acc = __builtin_amdgcn_mfma_f32_16x16x32_bf16(aF, bF, acc, 0, 0, 0);
            }
            const int m0 = w * 16 + quad * 4;
            const int p = ni * 16 + l15;
            ushort4 pk;
            pk.x = f2bf(fmaxf(acc[0] + b1s[m0 + 0], 0.f));
            pk.y = f2bf(fmaxf(acc[1] + b1s[m0 + 1], 0.f));
            pk.z = f2bf(fmaxf(acc[2] + b1s[m0 + 2], 0.f));
            pk.w = f2bf(fmaxf(acc[3] + b1s[m0 + 3], 0.f));
            *(ushort4*)&h1T[p * 72 + m0] = pk;
        }
    }
    __syncthreads();

    {   // layer 3: wave w owns m-tiles w*2, w*2+1
        #pragma unroll
        for (int mi = 0; mi < 2; ++mi) {
            const int m0 = (w * 2 + mi) * 16;
            #pragma unroll
            for (int ni = 0; ni < 2; ++ni) {
                floatx4 acc = (floatx4){0.f, 0.f, 0.f, 0.f};
                #pragma unroll
                for (int k0 = 0; k0 < 2; ++k0) {
                    short8 aF = *(const short8*)&W2s[(m0 + l15) * 72 + k0 * 32 + quad * 8];
                    short8 bF = *(const short8*)&h1T[(ni * 16 + l15) * 72 + k0 * 32 + quad * 8];
                    acc = __builtin_amdgcn_mfma_f32_16x16x32_bf16(aF, bF, acc, 0, 0, 0);
                }
                const int o2 = m0 + quad * 4;
                const int j = j0 + ni * 16 + l15;
                ushort4 pk;
                pk.x = f2bf(fmaxf(acc[0] + b2s[o2 + 0], 0.f));
                pk.y = f2bf(fmaxf(acc[1] + b2s[o2 + 1], 0.f));
                pk.z = f2bf(fmaxf(acc[2] + b2s[o2 + 2], 0.f));
                pk.w = f2bf(fmaxf(acc[3] + b2s[o2 + 3], 0.f));
                *(ushort4*)&F[((size_t)b * NPTS + j) * 384 + s * 128 + o2] = pk;
            }
        }
    }
}

// ---------------- Kernel 3: gather-max, 2 channels/lane (R15-passing) --------
__global__ __launch_bounds__(192) void maxgather_bf16(
    const unsigned short* __restrict__ F, const int* __restrict__ knn,
    unsigned short* __restrict__ pt)
{
    __shared__ int idxS[KNN];
    const int q = blockIdx.x;            // b*4096 + n
    const int b = q >> 12;
    const int t = threadIdx.x;           // channel-pair 0..191
    if (t < KNN) idxS[t] = knn[(size_t)q * KNN + t];
    __syncthreads();
    const unsigned short* Fb = F + (size_t)b * NPTS * 384 + t * 2;
    u16x2 m = (u16x2)0;
    #pragma unroll 8
    for (int k = 0; k < KNN; ++k) {
        u16x2 v = *(const u16x2*)(Fb + (size_t)idxS[k] * 384);
        m = __builtin_elementwise_max(m, v);
    }
    *(u16x2*)(pt + (size_t)q * 384 + t * 2) = m;
}

// ---------------- Kernel 4: bf16 MFMA GEMM + bias + relu (R10-passing) -------
template<int DO_ROWMAX>
__global__ __launch_bounds__(256) void gemm_bf16(
    const unsigned short* __restrict__ Wb, const unsigned short* __restrict__ Bt,
    const float* __restrict__ bias, void* __restrict__ outp,
    float* __restrict__ gfeat, int M, int K)
{
    __shared__ __align__(16) unsigned short As[128 * 40];
    __shared__ __align__(16) unsigned short Bs[128 * 40];
    __shared__ float biasS[128];
    __shared__ int redI[128];

    const int t = threadIdx.x;
    const int b = blockIdx.z;
    const int m0 = blockIdx.x * 128;
    const int n0 = blockIdx.y * 128;
    if (t < 128) biasS[t] = bias[m0 + t];
    if (DO_ROWMAX && t < 128) redI[t] = 0;

    const int wave = t >> 6, lane = t & 63, quad = lane >> 4, l15 = lane & 15;
    const int wr = wave >> 1, wc = wave & 1;

    const int am = t & 127, akh = t >> 7;
    const unsigned short* Wp = Wb + (size_t)(m0 + am) * K + akh * 16;
    const int bn = t >> 2, bq = t & 3;
    const unsigned short* Bp = Bt + ((size_t)b * NPTS + n0) * K;

    floatx4 acc[16];
    #pragma unroll
    for (int i = 0; i < 16; ++i) acc[i] = (floatx4){0.f, 0.f, 0.f, 0.f};

    const int nk = K >> 5;
    for (int kt = 0; kt < nk; ++kt) {
        const int k0 = kt << 5;
        uint4 av0 = *(const uint4*)(Wp + k0);
        uint4 av1 = *(const uint4*)(Wp + k0 + 8);
        uint4 bv0 = *(const uint4*)(Bp + (size_t)bn * K + k0 + bq * 8);
        uint4 bv1 = *(const uint4*)(Bp + (size_t)(bn + 64) * K + k0 + bq * 8);
        __syncthreads();
        {
            uint4* dst = (uint4*)&As[am * 40 + akh * 16];
            dst[0] = av0;
            dst[1] = av1;
            *(uint4*)&Bs[bn * 40 + bq * 8] = bv0;
            *(uint4*)&Bs[(bn + 64) * 40 + bq * 8] = bv1;
        }
        __syncthreads();
        short8 af[4], bfv[4];
        #pragma unroll
        for (int i = 0; i < 4; ++i)
            af[i] = *(const short8*)&As[(wr * 64 + i * 16 + l15) * 40 + quad * 8];
        #pragma unroll
        for (int j = 0; j < 4; ++j)
            bfv[j] = *(const short8*)&Bs[(wc * 64 + j * 16 + l15) * 40 + quad * 8];
        #pragma unroll
        for (int i = 0; i < 4; ++i)
            #pragma unroll
            for (int j = 0; j < 4; ++j)
                acc[i * 4 + j] = __builtin_amdgcn_mfma_f32_16x16x32_bf16(
                    af[i], bfv[j], acc[i * 4 + j], 0, 0, 0);
    }

    #pragma unroll
    for (int i = 0; i < 4; ++i) {
        const int mbase = wr * 64 + i * 16 + quad * 4;
        float rm0 = 0.f, rm1 = 0.f, rm2 = 0.f, rm3 = 0.f;
        #pragma unroll
        for (int j = 0; j < 4; ++j) {
            const int n = n0 + wc * 64 + j * 16 + l15;
            float v0 = fmaxf(acc[i * 4 + j][0] + biasS[mbase + 0], 0.f);
            float v1 = fmaxf(acc[i * 4 + j][1] + biasS[mbase + 1], 0.f);
            float v2 = fmaxf(acc[i * 4 + j][2] + biasS[mbase + 2], 0.f);
            float v3 = fmaxf(acc[i * 4 + j][3] + biasS[mbase + 3], 0.f);
            if (DO_ROWMAX) {
                rm0 = fmaxf(rm0, v0); rm1 = fmaxf(rm1, v1);
                rm2 = fmaxf(rm2, v2); rm3 = fmaxf(rm3, v3);
            }
            ushort4 pk;
            pk.x = f2bf(v0); pk.y = f2bf(v1); pk.z = f2bf(v2); pk.w = f2bf(v3);
            *(ushort4*)((unsigned short*)outp +
                        ((size_t)b * NPTS + n) * M + m0 + mbase) = pk;
        }
        if (DO_ROWMAX) {
            atomicMax(&redI[mbase + 0], __float_as_int(rm0));
            atomicMax(&redI[mbase + 1], __float_as_int(rm1));
            atomicMax(&redI[mbase + 2], __float_as_int(rm2));
            atomicMax(&redI[mbase + 3], __float_as_int(rm3));
        }
    }
    if (DO_ROWMAX) {
        __syncthreads();
        if (t < 128)
            atomicMax((int*)&gfeat[(size_t)b * 1024 + m0 + t], redI[t]);
    }
}

// ---------------- Kernel 5: fused head = gemm3 + gemm4 -----------------------
__global__ __launch_bounds__(256) void fused_head(
    const unsigned short* __restrict__ Wb2, const unsigned short* __restrict__ Wb3,
    const float* __restrict__ mb0, const float* __restrict__ mb1,
    const unsigned short* __restrict__ gft, float* __restrict__ outp)
{
    __shared__ __align__(16) unsigned short As[256 * 40];
    __shared__ __align__(16) unsigned short Bs[64 * 40];
    __shared__ __align__(16) unsigned short H[64 * 264];
    __shared__ float b0s[256];
    __shared__ float b1s[128];

    const int t = threadIdx.x;
    const int n0 = blockIdx.x * 64;
    const int b = blockIdx.y;
    b0s[t] = mb0[t];
    if (t < 128) b1s[t] = mb1[t];

    const int wave = t >> 6, lane = t & 63, quad = lane >> 4, l15 = lane & 15;

    const unsigned short* Ap = Wb2 + (size_t)t * 1024;
    const int bn = t >> 2, bq = t & 3;
    const unsigned short* Bp = gft + ((size_t)b * NPTS + n0) * 1024;

    floatx4 acc[16];
    #pragma unroll
    for (int i = 0; i < 16; ++i) acc[i] = (floatx4){0.f, 0.f, 0.f, 0.f};

    for (int kt = 0; kt < 32; ++kt) {
        const int k0 = kt << 5;
        uint4 a0 = *(const uint4*)(Ap + k0);
        uint4 a1 = *(const uint4*)(Ap + k0 + 8);
        uint4 a2 = *(const uint4*)(Ap + k0 + 16);
        uint4 a3 = *(const uint4*)(Ap + k0 + 24);
        uint4 bv = *(const uint4*)(Bp + (size_t)bn * 1024 + k0 + bq * 8);
        __syncthreads();
        *(uint4*)&As[t * 40 + 0]  = a0;
        *(uint4*)&As[t * 40 + 8]  = a1;
        *(uint4*)&As[t * 40 + 16] = a2;
        *(uint4*)&As[t * 40 + 24] = a3;
        *(uint4*)&Bs[bn * 40 + bq * 8] = bv;
        __syncthreads();
        short8 af[4], bfv[4];
        #pragma unroll
        for (int i = 0; i < 4; ++i)
            af[i] = *(const short8*)&As[(wave * 64 + i * 16 + l15) * 40 + quad * 8];
        #pragma unroll
        for (int j = 0; j < 4; ++j)
            bfv[j] = *(const short8*)&Bs[(j * 16 + l15) * 40 + quad * 8];
        #pragma unroll
        for (int i = 0; i < 4; ++i)
            #pragma unroll
            for (int j = 0; j < 4; ++j)
                acc[i * 4 + j] = __builtin_amdgcn_mfma_f32_16x16x32_bf16(
                    af[i], bfv[j], acc[i * 4 + j], 0, 0, 0);
    }
    #pragma unroll
    for (int i = 0; i < 4; ++i) {
        const int mbase = wave * 64 + i * 16 + quad * 4;
        #pragma unroll
        for (int j = 0; j < 4; ++j) {
            const int nl = j * 16 + l15;
            ushort4 pk;
            pk.x = f2bf(fmaxf(acc[i * 4 + j][0] + b0s[mbase + 0], 0.f));
            pk.y = f2bf(fmaxf(acc[i * 4 + j][1] + b0s[mbase + 1], 0.f));
            pk.z = f2bf(fmaxf(acc[i * 4 + j][2] + b0s[mbase + 2], 0.f));
            pk.w = f2bf(fmaxf(acc[i * 4 + j][3] + b0s[mbase + 3], 0.f));
            *(ushort4*)&H[nl * 264 + mbase] = pk;
        }
    }

    floatx4 acc2[8];
    #pragma unroll
    for (int i = 0; i < 8; ++i) acc2[i] = (floatx4){0.f, 0.f, 0.f, 0.f};
    const int am2 = t & 127, ah = t >> 7;

    for (int kt = 0; kt < 8; ++kt) {
        const int k0 = kt << 5;
        uint4 a0 = *(const uint4*)(Wb3 + (size_t)am2 * 256 + k0 + ah * 16);
        uint4 a1 = *(const uint4*)(Wb3 + (size_t)am2 * 256 + k0 + ah * 16 + 8);
        __syncthreads();
        *(uint4*)&As[am2 * 40 + ah * 16]     = a0;
        *(uint4*)&As[am2 * 40 + ah * 16 + 8] = a1;
        __syncthreads();
        short8 af2[2], bf2[4];
        #pragma unroll
        for (int i = 0; i < 2; ++i)
            af2[i] = *(const short8*)&As[(wave * 32 + i * 16 + l15) * 40 + quad * 8];
        #pragma unroll
        for (int j = 0; j < 4; ++j)
            bf2[j] = *(const short8*)&H[(j * 16 + l15) * 264 + k0 + quad * 8];
        #pragma unroll
        for (int i = 0; i < 2; ++i)
            #pragma unroll
            for (int j = 0; j < 4; ++j)
                acc2[i * 4 + j] = __builtin_amdgcn_mfma_f32_16x16x32_bf16(
                    af2[i], bf2[j], acc2[i * 4 + j], 0, 0, 0);
    }
    #pragma unroll
    for (int i = 0; i < 2; ++i) {
        const int m2 = wave * 32 + i * 16 + quad * 4;
        #pragma unroll
        for (int j = 0; j < 4; ++j) {
            const int n = n0 + j * 16 + l15;
            float* o = outp + ((size_t)b * 128 + m2) * NPTS + n;
            o[0 * NPTS] = fmaxf(acc2[i * 4 + j][0] + b1s[m2 + 0], 0.f);
            o[1 * NPTS] = fmaxf(acc2[i * 4 + j][1] + b1s[m2 + 1], 0.f);
            o[2 * NPTS] = fmaxf(acc2[i * 4 + j][2] + b1s[m2 + 2], 0.f);
            o[3 * NPTS] = fmaxf(acc2[i * 4 + j][3] + b1s[m2 + 3], 0.f);
        }
    }
}

extern "C" void kernel_launch(void* const* d_in, const int* in_sizes, int n_in,
                              void* d_out, int out_size, void* d_ws, size_t ws_size,
                              hipStream_t stream)
{
    const float* x   = (const float*)d_in[0];
    const float* sW0 = (const float*)d_in[1];
    const float* sb0 = (const float*)d_in[2];
    const float* sW1 = (const float*)d_in[3];
    const float* sb1 = (const float*)d_in[4];
    const float* sW2 = (const float*)d_in[5];
    const float* sb2 = (const float*)d_in[6];
    const float* gW0 = (const float*)d_in[7];
    const float* gb0 = (const float*)d_in[8];
    const float* gW1 = (const float*)d_in[9];
    const float* gb1 = (const float*)d_in[10];
    const float* mW0 = (const float*)d_in[11];
    const float* mb0 = (const float*)d_in[12];
    const float* mW1 = (const float*)d_in[13];
    const float* mb1 = (const float*)d_in[14];
    float* outp = (float*)d_out;

    char* ws = (char*)d_ws;
    int*            idx     = (int*)(ws);                        // 2 MB
    float4*         pts4    = (float4*)(ws + 2097152u);          // 256 KB
    unsigned short* Wb0     = (unsigned short*)(ws + 2359296u);  // 192 KB  gW0 bf16
    unsigned short* Wb1     = (unsigned short*)(ws + 2555904u);  // 512 KB  gW1 bf16
    unsigned short* Wb2     = (unsigned short*)(ws + 3080192u);  // 512 KB  mW0 bf16
    unsigned short* Wb3     = (unsigned short*)(ws + 3604480u);  // 64 KB   mW1 bf16
    unsigned short* Wb4     = (unsigned short*)(ws + 3670016u);  // 24 KB   sW1 bf16
    unsigned short* Wb5     = (unsigned short*)(ws + 3694592u);  // 48 KB   sW2 bf16
    unsigned short* F       = (unsigned short*)(ws + 4194304u);  // 12.6 MB [b][n][384] bf16
    unsigned short* point_t = (unsigned short*)(ws + 18874368u); // 12.6 MB [b][n][384] bf16
    unsigned short* gf0t    = (unsigned short*)(ws + 33554432u); // 8.4 MB  [b][n][256] bf16
    unsigned short* gft     = (unsigned short*)(ws + 50331648u); // 33.6 MB [b][n][1024] bf16

    prep_all<<<dim3(2768), dim3(256), 0, stream>>>(
        x, pts4, gW0, gW1, mW0, mW1, sW1, sW2, Wb0, Wb1, Wb2, Wb3, Wb4, Wb5);
    knn_kernel13<<<dim3(16384), dim3(256), 0, stream>>>(pts4, idx);
    pointmlp_mfma<<<dim3(512, 3), dim3(256), 0, stream>>>(
        x, sW0, sb0, Wb4, sb1, Wb5, sb2, F);
    maxgather_bf16<<<dim3(16384), dim3(192), 0, stream>>>(F, idx, point_t);
    gemm_bf16<0><<<dim3(2, 32, 4), dim3(256), 0, stream>>>(
        Wb0, point_t, gb0, gf0t, nullptr, 256, 384);
    gemm_bf16<1><<<dim3(8, 32, 4), dim3(256), 0, stream>>>(
        Wb1, gf0t, gb1, gft, outp, 1024, 256);
    fused_head<<<dim3(64, 4), dim3(256), 0, stream>>>(
        Wb2, Wb3, mb0, mb1, gft, outp + 4096);
}